// Round 2
// baseline (487.007 us; speedup 1.0000x reference)
//
#include <hip/hip_runtime.h>
#include <hip/hip_bf16.h>

#define Bq 4
#define Sq 2048
#define Dq 1024
#define Hq 16
#define HDq 64
#define Mq (Bq*Sq)   // 8192

typedef unsigned short u16;
typedef __attribute__((ext_vector_type(8))) __bf16 b16x8;
typedef __attribute__((ext_vector_type(4))) float f32x4;
typedef __attribute__((ext_vector_type(4))) unsigned int u32x4;

__device__ inline float bf2f(u16 h){ union{unsigned u; float f;} v; v.u = ((unsigned)h)<<16; return v.f; }
__device__ inline u16 f2bf(float f){ union{float f; unsigned u;} v; v.f=f; unsigned r = v.u + 0x7FFFu + ((v.u>>16)&1u); return (u16)(r>>16); }
// dual-dtype scalar load: isf32 ? fp32[i] : bf16[i]
__device__ inline float ld_elem(const void* p, size_t i, int isf32){
  return isf32 ? ((const float*)p)[i] : bf2f(((const u16*)p)[i]);
}

// ---- dtype probe: fp32 buffers read as u16 have uniform-random halves -> huge bf16 exponents
__global__ void detect_dtype(const unsigned* __restrict__ x, int* __restrict__ flag){
  __shared__ int cnt;
  if(threadIdx.x==0) cnt=0;
  __syncthreads();
  int local=0;
  for(int i=threadIdx.x;i<2048;i+=256){   // first 8KB, safe under either dtype
    unsigned w = x[i];
    unsigned e0 = (w>>7)&0xFFu, e1 = (w>>23)&0xFFu;
    if(e0>=0x90u) local++;
    if(e1>=0x90u) local++;
  }
  atomicAdd(&cnt, local);
  __syncthreads();
  if(threadIdx.x==0) *flag = (cnt>64) ? 1 : 0;
}

// ---- x -> canonical bf16 (copy if already bf16)
__global__ __launch_bounds__(256) void convert_x(const void* __restrict__ x, u16* __restrict__ xc,
                                                 const int* __restrict__ flag, int n){
  const int f = *flag;
  int i = (blockIdx.x*256 + threadIdx.x)*8;
  if(i>=n) return;
  if(f){
    const float* xf=(const float*)x;
    #pragma unroll
    for(int j=0;j<8;j++) xc[i+j] = f2bf(xf[i+j]);
  } else {
    *(u32x4*)&xc[i] = *(const u32x4*)((const u16*)x + i);
  }
}

// ---- weight transpose+convert: W[k][n] (either dtype) -> WT[n][k] bf16
__global__ __launch_bounds__(256) void transpose_w(
    const void* __restrict__ W0, const void* __restrict__ W1,
    const void* __restrict__ W2, const void* __restrict__ W3,
    u16* __restrict__ T0, u16* __restrict__ T1,
    u16* __restrict__ T2, u16* __restrict__ T3,
    const int* __restrict__ flag){
  __shared__ u16 tile[64][65];
  const int f = *flag;
  const int z = blockIdx.z;
  const void* src = (z==0)?W0:(z==1)?W1:(z==2)?W2:W3;
  u16*       dst = (z==0)?T0:(z==1)?T1:(z==2)?T2:T3;
  const int t = threadIdx.x;
  const int k0 = blockIdx.x*64, n0 = blockIdx.y*64;
  #pragma unroll
  for(int r=0;r<16;r++){
    int row = r*4 + (t>>6), col = t&63;
    tile[row][col] = f2bf(ld_elem(src, (size_t)(k0+row)*Dq + n0 + col, f));
  }
  __syncthreads();
  #pragma unroll
  for(int r=0;r<16;r++){
    int row = r*4 + (t>>6), col = t&63;
    dst[(size_t)(n0+row)*Dq + k0 + col] = tile[col][row];
  }
}

// ---------------- GEMM: C[M][N] = A[M][K] * Bt[N][K]^T ----------------
// MODE 0: A=xc (bf16), z selects {WqT,WkT,WvT}; epilogue splits heads
// MODE 1: out-proj: out[m*D+n] = acc + bias[n], written bf16 or fp32 per flag
template<int MODE>
__global__ __launch_bounds__(256) void gemm128(
    const u16* __restrict__ A,
    const u16* __restrict__ B0, const u16* __restrict__ B1, const u16* __restrict__ B2,
    u16* __restrict__ O0, u16* __restrict__ O1, u16* __restrict__ O2,
    void* __restrict__ Og, const void* __restrict__ bias, const int* __restrict__ flag){
  __shared__ u16 Al[128][40];
  __shared__ u16 Bl[128][40];
  const int f = (MODE==1) ? *flag : 0;
  const int t = threadIdx.x;
  const int lane = t & 63, wave = t >> 6;
  const int quad = lane >> 4, l16 = lane & 15;
  const int wr = wave >> 1, wc = wave & 1;
  const int m0 = blockIdx.y*128, n0 = blockIdx.x*128;
  const u16* Bt = B0;
  int z = 0;
  if (MODE==0){ z = blockIdx.z; Bt = (z==0)?B0:((z==1)?B1:B2); }

  f32x4 acc[4][4] = {};

  for(int k0=0;k0<Dq;k0+=32){
    #pragma unroll
    for(int r=0;r<2;r++){
      int idx = t + (r<<8);
      int row = idx>>2, kk = (idx&3)<<3;
      *(u32x4*)&Al[row][kk] = *(const u32x4*)&A [(size_t)(m0+row)*Dq + k0 + kk];
      *(u32x4*)&Bl[row][kk] = *(const u32x4*)&Bt[(size_t)(n0+row)*Dq + k0 + kk];
    }
    __syncthreads();
    b16x8 af[4], bfr[4];
    #pragma unroll
    for(int i=0;i<4;i++) af[i]  = *(const b16x8*)&Al[wr*64 + i*16 + l16][quad*8];
    #pragma unroll
    for(int j=0;j<4;j++) bfr[j] = *(const b16x8*)&Bl[wc*64 + j*16 + l16][quad*8];
    #pragma unroll
    for(int i=0;i<4;i++)
      #pragma unroll
      for(int j=0;j<4;j++)
        acc[i][j] = __builtin_amdgcn_mfma_f32_16x16x32_bf16(af[i], bfr[j], acc[i][j], 0,0,0);
    __syncthreads();
  }

  #pragma unroll
  for(int i=0;i<4;i++){
    #pragma unroll
    for(int j=0;j<4;j++){
      int n = n0 + wc*64 + j*16 + l16;
      #pragma unroll
      for(int r=0;r<4;r++){
        int m = m0 + wr*64 + i*16 + quad*4 + r;   // C/D: row=quad*4+reg, col=l16
        float c = acc[i][j][r];
        if (MODE==1){
          float c2 = c + ld_elem(bias, n, f);
          if (f) ((float*)Og)[(size_t)m*Dq + n] = c2;
          else   ((u16*)Og)[(size_t)m*Dq + n]   = f2bf(c2);
        } else {
          int b = m >> 11, s = m & 2047;
          int h = n >> 6,  hd = n & 63;
          if (z==0)      O0[(((size_t)(b*Hq + h))*Sq + s)*HDq + hd] = f2bf(c);
          else if (z==1) O1[(((size_t)(b*Hq + h))*Sq + s)*HDq + hd] = f2bf(c);
          else           O2[(((size_t)(b*Hq + h))*HDq + hd)*Sq + s] = f2bf(c);
        }
      }
    }
  }
}

// ---------------- flash attention (online softmax), mask: key <= q+1 ----------------
__global__ __launch_bounds__(256) void flash_attn(
    const u16* __restrict__ Q, const u16* __restrict__ K,
    const u16* __restrict__ VT, u16* __restrict__ C){
  __shared__ u16 Kt[64][72];      // [key][hd]
  __shared__ u16 Vt[64][72];      // [hd][key]
  __shared__ u16 Pl[4][16][72];   // per-wave P: C-layout -> A-layout round-trip
  const int t = threadIdx.x;
  const int lane = t&63, wave = t>>6, quad = lane>>4, l16 = lane&15;
  const int qt = blockIdx.x, bh = blockIdx.y;
  const int b = bh >> 4, h = bh & 15;
  const int q0 = qt*64;
  const u16* Qh = Q  + (size_t)bh*Sq*HDq;
  const u16* Kh = K  + (size_t)bh*Sq*HDq;
  const u16* Vh = VT + (size_t)bh*HDq*Sq;

  b16x8 aq0, aq1;
  {
    const u16* qp = Qh + (size_t)(q0 + wave*16 + l16)*HDq + quad*8;
    aq0 = *(const b16x8*)qp;
    aq1 = *(const b16x8*)(qp + 32);
  }
  const f32x4 fzero = {0.f,0.f,0.f,0.f};
  float m_i[4], l_i[4];
  f32x4 Oa[4];
  #pragma unroll
  for(int r=0;r<4;r++){ m_i[r] = -__builtin_inff(); l_i[r] = 0.f; }
  #pragma unroll
  for(int j=0;j<4;j++) Oa[j] = fzero;

  const int nkt = (qt + 2 < Sq/64) ? (qt + 2) : (Sq/64);
  for(int kt=0; kt<nkt; kt++){
    __syncthreads();
    #pragma unroll
    for(int r=0;r<2;r++){
      int idx = t + (r<<8);
      int row = idx>>3, cc = (idx&7)<<3;
      *(u32x4*)&Kt[row][cc] = *(const u32x4*)&Kh[(size_t)(kt*64+row)*HDq + cc];
      *(u32x4*)&Vt[row][cc] = *(const u32x4*)&Vh[(size_t)row*Sq + kt*64 + cc];
    }
    __syncthreads();

    f32x4 sc[4];
    #pragma unroll
    for(int jn=0;jn<4;jn++){
      f32x4 s = fzero;
      b16x8 bk0 = *(const b16x8*)&Kt[jn*16 + l16][quad*8];
      b16x8 bk1 = *(const b16x8*)&Kt[jn*16 + l16][32 + quad*8];
      s = __builtin_amdgcn_mfma_f32_16x16x32_bf16(aq0, bk0, s, 0,0,0);
      s = __builtin_amdgcn_mfma_f32_16x16x32_bf16(aq1, bk1, s, 0,0,0);
      sc[jn] = s;
    }
    const int qbase = q0 + wave*16 + quad*4;
    #pragma unroll
    for(int jn=0;jn<4;jn++){
      int kg = kt*64 + jn*16 + l16;
      #pragma unroll
      for(int r=0;r<4;r++){
        float sv = sc[jn][r]*0.125f;                 // 1/sqrt(64)
        if (kg > qbase + r + 1) sv = -__builtin_inff();   // tril(k=1): key <= q+1
        sc[jn][r] = sv;
      }
    }
    float alpha[4];
    #pragma unroll
    for(int r=0;r<4;r++){
      float v = fmaxf(fmaxf(sc[0][r],sc[1][r]), fmaxf(sc[2][r],sc[3][r]));
      #pragma unroll
      for(int off=1; off<16; off<<=1) v = fmaxf(v, __shfl_xor(v, off, 64));
      float mn = fmaxf(m_i[r], v);
      alpha[r] = __expf(m_i[r] - mn);
      m_i[r] = mn;
    }
    float rsum[4] = {0.f,0.f,0.f,0.f};
    #pragma unroll
    for(int jn=0;jn<4;jn++)
      #pragma unroll
      for(int r=0;r<4;r++){
        float p = __expf(sc[jn][r] - m_i[r]);
        sc[jn][r] = p;
        rsum[r] += p;
      }
    #pragma unroll
    for(int r=0;r<4;r++){
      #pragma unroll
      for(int off=1; off<16; off<<=1) rsum[r] += __shfl_xor(rsum[r], off, 64);
      l_i[r] = l_i[r]*alpha[r] + rsum[r];
    }
    #pragma unroll
    for(int j=0;j<4;j++)
      #pragma unroll
      for(int r=0;r<4;r++) Oa[j][r] *= alpha[r];
    #pragma unroll
    for(int jn=0;jn<4;jn++)
      #pragma unroll
      for(int r=0;r<4;r++)
        Pl[wave][quad*4+r][jn*16+l16] = f2bf(sc[jn][r]);
    __syncthreads();
    #pragma unroll
    for(int ks=0;ks<2;ks++){
      b16x8 ap = *(const b16x8*)&Pl[wave][l16][ks*32 + quad*8];
      #pragma unroll
      for(int jd=0;jd<4;jd++){
        b16x8 bv = *(const b16x8*)&Vt[jd*16 + l16][ks*32 + quad*8];
        Oa[jd] = __builtin_amdgcn_mfma_f32_16x16x32_bf16(ap, bv, Oa[jd], 0,0,0);
      }
    }
  }
  #pragma unroll
  for(int r=0;r<4;r++){
    int s = q0 + wave*16 + quad*4 + r;
    float inv = 1.0f / l_i[r];
    #pragma unroll
    for(int jd=0;jd<4;jd++)
      C[((size_t)(b*Sq + s))*Dq + h*HDq + jd*16 + l16] = f2bf(Oa[jd][r]*inv);
  }
}

// ---------------- launch ----------------
extern "C" void kernel_launch(void* const* d_in, const int* in_sizes, int n_in,
                              void* d_out, int out_size, void* d_ws, size_t ws_size,
                              hipStream_t stream){
  const void* x  = d_in[0];
  const void* Wq = d_in[1];
  const void* Wk = d_in[2];
  const void* Wv = d_in[3];
  const void* Wo = d_in[4];
  const void* bo = d_in[5];

  char* ws = (char*)d_ws;
  size_t off = 0;
  auto wsalloc = [&](size_t bytes)->void*{
    void* p = ws + off; off += (bytes + 255) & ~(size_t)255; return p;
  };
  int* flag = (int*)wsalloc(256);
  u16* WqT = (u16*)wsalloc((size_t)Dq*Dq*2);
  u16* WkT = (u16*)wsalloc((size_t)Dq*Dq*2);
  u16* WvT = (u16*)wsalloc((size_t)Dq*Dq*2);
  u16* WoT = (u16*)wsalloc((size_t)Dq*Dq*2);
  u16* xc  = (u16*)wsalloc((size_t)Mq*Dq*2);   // canonical bf16 x; reused as Cb after gemm<0>
  u16* Qb  = (u16*)wsalloc((size_t)Mq*Dq*2);   // [b,h,s,hd]
  u16* Kb  = (u16*)wsalloc((size_t)Mq*Dq*2);   // [b,h,s,hd]
  u16* VTb = (u16*)wsalloc((size_t)Mq*Dq*2);   // [b,h,hd,s]
  u16* Cb  = (u16*)wsalloc((size_t)Mq*Dq*2);   // [b,s,d] attention output

  detect_dtype<<<1, 256, 0, stream>>>((const unsigned*)x, flag);
  convert_x<<<dim3(Mq*Dq/8/256), 256, 0, stream>>>(x, xc, flag, Mq*Dq);
  transpose_w<<<dim3(16,16,4), 256, 0, stream>>>(Wq,Wk,Wv,Wo, WqT,WkT,WvT,WoT, flag);
  gemm128<0><<<dim3(Dq/128, Mq/128, 3), 256, 0, stream>>>(xc, WqT,WkT,WvT, Qb,Kb,VTb, nullptr, nullptr, flag);
  flash_attn<<<dim3(Sq/64, Bq*Hq), 256, 0, stream>>>(Qb, Kb, VTb, Cb);
  gemm128<1><<<dim3(Dq/128, Mq/128, 1), 256, 0, stream>>>(Cb, WoT,WoT,WoT, nullptr,nullptr,nullptr, d_out, bo, flag);
}

// Round 3
// 310.885 us; speedup vs baseline: 1.5665x; 1.5665x over previous
//
#include <hip/hip_runtime.h>
#include <hip/hip_bf16.h>

#define Bq 4
#define Sq 2048
#define Dq 1024
#define Hq 16
#define HDq 64
#define Mq (Bq*Sq)   // 8192

typedef unsigned short u16;
typedef __attribute__((ext_vector_type(8))) __bf16 b16x8;
typedef __attribute__((ext_vector_type(4))) float f32x4;
typedef __attribute__((ext_vector_type(4))) unsigned int u32x4;

__device__ inline float bf2f(u16 h){ union{unsigned u; float f;} v; v.u = ((unsigned)h)<<16; return v.f; }
__device__ inline u16 f2bf(float f){ union{float f; unsigned u;} v; v.f=f; unsigned r = v.u + 0x7FFFu + ((v.u>>16)&1u); return (u16)(r>>16); }
__device__ inline u16 truncbf(float f){ union{float f; unsigned u;} v; v.f=f; return (u16)(v.u>>16); }
__device__ inline float ld_elem(const void* p, size_t i, int isf32){
  return isf32 ? ((const float*)p)[i] : bf2f(((const u16*)p)[i]);
}
// async global->LDS, 16B per lane; LDS dest must be wave-uniform-base + lane*16
__device__ inline void ld16(const u16* g, u16* l){
  __builtin_amdgcn_global_load_lds((const __attribute__((address_space(1))) void*)g,
                                   (__attribute__((address_space(3))) void*)l, 16, 0, 0);
}

#if __has_builtin(__builtin_amdgcn_exp2f)
#define EXP2(x) __builtin_amdgcn_exp2f(x)
#else
#define EXP2(x) __expf((x)*0.69314718056f)
#endif
// 0.125 (1/sqrt(64)) * log2(e): softmax done in exp2 domain, no max subtraction
#define SCALE_LOG2E 0.18033688011112042f

// ---- dtype probe: fp32 buffers read as u16 halves -> huge bf16 exponents
__global__ void detect_dtype(const unsigned* __restrict__ x, int* __restrict__ flag){
  __shared__ int cnt;
  if(threadIdx.x==0) cnt=0;
  __syncthreads();
  int local=0;
  for(int i=threadIdx.x;i<2048;i+=256){
    unsigned w = x[i];
    if(((w>>7)&0xFFu)>=0x90u) local++;
    if(((w>>23)&0xFFu)>=0x90u) local++;
  }
  atomicAdd(&cnt, local);
  __syncthreads();
  if(threadIdx.x==0) *flag = (cnt>64) ? 1 : 0;
}

// ---- x -> canonical bf16
__global__ __launch_bounds__(256) void convert_x(const void* __restrict__ x, u16* __restrict__ xc,
                                                 const int* __restrict__ flag, int n){
  const int f = *flag;
  int i = (blockIdx.x*256 + threadIdx.x)*8;
  if(i>=n) return;
  if(f){
    const float* xf=(const float*)x;
    #pragma unroll
    for(int j=0;j<8;j++) xc[i+j] = f2bf(xf[i+j]);
  } else {
    *(u32x4*)&xc[i] = *(const u32x4*)((const u16*)x + i);
  }
}

// ---- weight transpose+convert: W[k][n] -> WT[n][k] bf16
__global__ __launch_bounds__(256) void transpose_w(
    const void* __restrict__ W0, const void* __restrict__ W1,
    const void* __restrict__ W2, const void* __restrict__ W3,
    u16* __restrict__ T0, u16* __restrict__ T1,
    u16* __restrict__ T2, u16* __restrict__ T3,
    const int* __restrict__ flag){
  __shared__ u16 tile[64][65];
  const int f = *flag;
  const int z = blockIdx.z;
  const void* src = (z==0)?W0:(z==1)?W1:(z==2)?W2:W3;
  u16*       dst = (z==0)?T0:(z==1)?T1:(z==2)?T2:T3;
  const int t = threadIdx.x;
  const int k0 = blockIdx.x*64, n0 = blockIdx.y*64;
  #pragma unroll
  for(int r=0;r<16;r++){
    int row = r*4 + (t>>6), col = t&63;
    tile[row][col] = f2bf(ld_elem(src, (size_t)(k0+row)*Dq + n0 + col, f));
  }
  __syncthreads();
  #pragma unroll
  for(int r=0;r<16;r++){
    int row = r*4 + (t>>6), col = t&63;
    dst[(size_t)(n0+row)*Dq + k0 + col] = tile[col][row];
  }
}

// ---------------- GEMM (m97-style): C = A * Bt^T, global_load_lds staging ----------------
template<int MODE>
__global__ __launch_bounds__(256) void gemm128(
    const u16* __restrict__ A,
    const u16* __restrict__ B0, const u16* __restrict__ B1, const u16* __restrict__ B2,
    u16* __restrict__ O0, u16* __restrict__ O1, u16* __restrict__ O2,
    void* __restrict__ Og, const void* __restrict__ bias, const int* __restrict__ flag){
  __shared__ u16 Al[128*32];   // unpadded: required by global_load_lds lane-contiguity
  __shared__ u16 Bl[128*32];
  const int f = (MODE==1) ? *flag : 0;
  const int t = threadIdx.x;
  const int lane = t & 63, wave = t >> 6;
  const int quad = lane >> 4, l16 = lane & 15;
  const int wr = wave >> 1, wc = wave & 1;
  const int m0 = blockIdx.y*128, n0 = blockIdx.x*128;
  const u16* Bt = B0;
  int z = 0;
  if (MODE==0){ z = blockIdx.z; Bt = (z==0)?B0:((z==1)?B1:B2); }

  f32x4 acc[4][4] = {};

  for(int k0=0;k0<Dq;k0+=32){
    #pragma unroll
    for(int r=0;r<2;r++){
      int idx = t + (r<<8);            // 0..511, lane-consecutive within wave
      int row = idx>>2, kk = (idx&3)<<3;
      ld16(&A [(size_t)(m0+row)*Dq + k0 + kk], Al + idx*8);
      ld16(&Bt[(size_t)(n0+row)*Dq + k0 + kk], Bl + idx*8);
    }
    __syncthreads();   // drains the LDS-DMA (vmcnt) + publishes
    b16x8 af[4], bfr[4];
    #pragma unroll
    for(int i=0;i<4;i++) af[i]  = *(const b16x8*)&Al[(wr*64 + i*16 + l16)*32 + quad*8];
    #pragma unroll
    for(int j=0;j<4;j++) bfr[j] = *(const b16x8*)&Bl[(wc*64 + j*16 + l16)*32 + quad*8];
    #pragma unroll
    for(int i=0;i<4;i++)
      #pragma unroll
      for(int j=0;j<4;j++)
        acc[i][j] = __builtin_amdgcn_mfma_f32_16x16x32_bf16(af[i], bfr[j], acc[i][j], 0,0,0);
    __syncthreads();
  }

  #pragma unroll
  for(int i=0;i<4;i++){
    #pragma unroll
    for(int j=0;j<4;j++){
      int n = n0 + wc*64 + j*16 + l16;
      #pragma unroll
      for(int r=0;r<4;r++){
        int m = m0 + wr*64 + i*16 + quad*4 + r;   // C/D: row=quad*4+reg, col=l16
        float c = acc[i][j][r];
        if (MODE==1){
          float c2 = c + ld_elem(bias, n, f);
          if (f) ((float*)Og)[(size_t)m*Dq + n] = c2;
          else   ((u16*)Og)[(size_t)m*Dq + n]   = f2bf(c2);
        } else {
          int b = m >> 11, s = m & 2047;
          int h = n >> 6,  hd = n & 63;
          if (z==0)      O0[(((size_t)(b*Hq + h))*Sq + s)*HDq + hd] = f2bf(c);
          else if (z==1) O1[(((size_t)(b*Hq + h))*Sq + s)*HDq + hd] = f2bf(c);
          else           O2[(((size_t)(b*Hq + h))*HDq + hd)*Sq + s] = f2bf(c);
        }
      }
    }
  }
}

// ---------------- flash attention v2 ----------------
// - paired q-tiles (qa=p, qb=31-p): constant per-block work, shared K/V staging
// - no max-subtraction (scores bounded; exp2 domain), l via ones-column MFMA
// - K/V: unpadded [64][64] tiles, XOR-swizzled column groups (g_phys = g_log ^ (row&7)),
//   staged by global_load_lds (dest = base + lane*16 in slot order; source addr carries swizzle)
__global__ __launch_bounds__(256,4) void flash_attn(
    const u16* __restrict__ Q, const u16* __restrict__ K,
    const u16* __restrict__ VT, u16* __restrict__ C){
  __shared__ u16 Kt[64*64];     // [key][hd], swizzled groups
  __shared__ u16 Vt[64*64];     // [hd][key], swizzled groups
  __shared__ u16 Pl[4][16][72]; // per-wave P round-trip (C-layout -> A-layout)
  const int t = threadIdx.x;
  const int lane = t&63, wave = t>>6, quad = lane>>4, l16 = lane&15;
  const int p = blockIdx.x, bh = blockIdx.y;
  const int qa = p, qb = 31 - p;          // paired tiles: total work 35 iters, constant
  const int b = bh >> 4, h = bh & 15;
  const u16* Qh = Q  + (size_t)bh*Sq*HDq;
  const u16* Kh = K  + (size_t)bh*Sq*HDq;
  const u16* Vh = VT + (size_t)bh*HDq*Sq;

  b16x8 aq[2][2];
  #pragma unroll
  for(int tt=0;tt<2;tt++){
    int qq0 = (tt ? qb : qa)*64;
    const u16* qp = Qh + (size_t)(qq0 + wave*16 + l16)*HDq + quad*8;
    aq[tt][0] = *(const b16x8*)qp;
    aq[tt][1] = *(const b16x8*)(qp + 32);
  }
  b16x8 vone;
  #pragma unroll
  for(int i=0;i<8;i++) vone[i] = (__bf16)1.0f;

  const f32x4 fzero = {0.f,0.f,0.f,0.f};
  f32x4 Oa[2][4]; f32x4 lacc[2];
  #pragma unroll
  for(int tt=0;tt<2;tt++){ lacc[tt]=fzero; for(int j=0;j<4;j++) Oa[tt][j]=fzero; }

  const int nkt = (qb+2 < 32) ? (qb+2) : 32;
  for(int kt=0; kt<nkt; kt++){
    __syncthreads();   // prior iteration's reads of Kt/Vt complete
    #pragma unroll
    for(int r=0;r<2;r++){
      int idx = t + (r<<8);            // slot 0..511 (16B each)
      int row = idx>>3, g = idx&7;
      int c = ((g ^ (row&7)))<<3;      // source column carries the swizzle
      ld16(Kh + (size_t)(kt*64+row)*HDq + c, Kt + idx*8);
      ld16(Vh + (size_t)row*Sq + (size_t)kt*64 + c, Vt + idx*8);
    }
    __syncthreads();   // drain DMA

    #pragma unroll
    for(int tt=0;tt<2;tt++){
      if (tt==0 && kt >= qa+2) continue;      // light tile done (wave-uniform)
      const int qq0 = (tt ? qb : qa)*64;
      // S = Q K^T : B-frag rows = keys, swizzled groups
      f32x4 sc[4];
      #pragma unroll
      for(int jn=0;jn<4;jn++){
        int krow = jn*16 + l16;
        const u16* kp = &Kt[krow*64];
        int ph = quad ^ (krow&7);
        b16x8 bk0 = *(const b16x8*)&kp[ph*8];
        b16x8 bk1 = *(const b16x8*)&kp[(ph^4)*8];
        f32x4 s = fzero;
        s = __builtin_amdgcn_mfma_f32_16x16x32_bf16(aq[tt][0], bk0, s, 0,0,0);
        s = __builtin_amdgcn_mfma_f32_16x16x32_bf16(aq[tt][1], bk1, s, 0,0,0);
        sc[jn] = s;
      }
      // scale to exp2 domain + causal(+1) mask, p = exp2; truncate-pack to LDS
      const int qbase = qq0 + wave*16 + quad*4;
      #pragma unroll
      for(int jn=0;jn<4;jn++){
        int kg = kt*64 + jn*16 + l16;
        #pragma unroll
        for(int r=0;r<4;r++){
          float sv = sc[jn][r]*SCALE_LOG2E;
          if (kg > qbase + r + 1) sv = -__builtin_inff();
          Pl[wave][quad*4+r][jn*16+l16] = truncbf(EXP2(sv));
        }
      }
      // O += P V ; l += P . 1   (no barrier: Pl is wave-private)
      #pragma unroll
      for(int ks=0;ks<2;ks++){
        b16x8 ap = *(const b16x8*)&Pl[wave][l16][ks*32 + quad*8];
        #pragma unroll
        for(int jd=0;jd<4;jd++){
          int hd = jd*16 + l16;
          int ph = (ks*4+quad) ^ (hd&7);
          b16x8 bv = *(const b16x8*)&Vt[hd*64 + ph*8];
          Oa[tt][jd] = __builtin_amdgcn_mfma_f32_16x16x32_bf16(ap, bv, Oa[tt][jd], 0,0,0);
        }
        lacc[tt] = __builtin_amdgcn_mfma_f32_16x16x32_bf16(ap, vone, lacc[tt], 0,0,0);
      }
    }
  }
  // epilogue: ctx[b, s, h*64+hd]
  #pragma unroll
  for(int tt=0;tt<2;tt++){
    const int qq0 = (tt ? qb : qa)*64;
    #pragma unroll
    for(int r=0;r<4;r++){
      int s = qq0 + wave*16 + quad*4 + r;
      float inv = 1.0f / lacc[tt][r];
      #pragma unroll
      for(int jd=0;jd<4;jd++)
        C[((size_t)(b*Sq + s))*Dq + h*HDq + jd*16 + l16] = f2bf(Oa[tt][jd][r]*inv);
    }
  }
}

// ---------------- launch ----------------
extern "C" void kernel_launch(void* const* d_in, const int* in_sizes, int n_in,
                              void* d_out, int out_size, void* d_ws, size_t ws_size,
                              hipStream_t stream){
  const void* x  = d_in[0];
  const void* Wq = d_in[1];
  const void* Wk = d_in[2];
  const void* Wv = d_in[3];
  const void* Wo = d_in[4];
  const void* bo = d_in[5];

  char* ws = (char*)d_ws;
  size_t off = 0;
  auto wsalloc = [&](size_t bytes)->void*{
    void* p = ws + off; off += (bytes + 255) & ~(size_t)255; return p;
  };
  int* flag = (int*)wsalloc(256);
  u16* WqT = (u16*)wsalloc((size_t)Dq*Dq*2);
  u16* WkT = (u16*)wsalloc((size_t)Dq*Dq*2);
  u16* WvT = (u16*)wsalloc((size_t)Dq*Dq*2);
  u16* WoT = (u16*)wsalloc((size_t)Dq*Dq*2);
  u16* xc  = (u16*)wsalloc((size_t)Mq*Dq*2);
  u16* Qb  = (u16*)wsalloc((size_t)Mq*Dq*2);   // [b,h,s,hd]
  u16* Kb  = (u16*)wsalloc((size_t)Mq*Dq*2);   // [b,h,s,hd]
  u16* VTb = (u16*)wsalloc((size_t)Mq*Dq*2);   // [b,h,hd,s]
  u16* Cb  = (u16*)wsalloc((size_t)Mq*Dq*2);   // [b,s,d]

  detect_dtype<<<1, 256, 0, stream>>>((const unsigned*)x, flag);
  convert_x<<<dim3(Mq*Dq/8/256), 256, 0, stream>>>(x, xc, flag, Mq*Dq);
  transpose_w<<<dim3(16,16,4), 256, 0, stream>>>(Wq,Wk,Wv,Wo, WqT,WkT,WvT,WoT, flag);
  gemm128<0><<<dim3(Dq/128, Mq/128, 3), 256, 0, stream>>>(xc, WqT,WkT,WvT, Qb,Kb,VTb, nullptr, nullptr, flag);
  flash_attn<<<dim3(16, Bq*Hq), 256, 0, stream>>>(Qb, Kb, VTb, Cb);
  gemm128<1><<<dim3(Dq/128, Mq/128, 1), 256, 0, stream>>>(Cb, WoT,WoT,WoT, nullptr,nullptr,nullptr, d_out, bo, flag);
}

// Round 4
// 309.432 us; speedup vs baseline: 1.5739x; 1.0047x over previous
//
#include <hip/hip_runtime.h>
#include <hip/hip_bf16.h>

#define Bq 4
#define Sq 2048
#define Dq 1024
#define Hq 16
#define HDq 64
#define Mq (Bq*Sq)   // 8192

typedef unsigned short u16;
typedef __attribute__((ext_vector_type(8))) __bf16 b16x8;
typedef __attribute__((ext_vector_type(4))) float f32x4;
typedef __attribute__((ext_vector_type(4))) unsigned int u32x4;

__device__ inline float bf2f(u16 h){ union{unsigned u; float f;} v; v.u = ((unsigned)h)<<16; return v.f; }
__device__ inline u16 f2bf(float f){ union{float f; unsigned u;} v; v.f=f; unsigned r = v.u + 0x7FFFu + ((v.u>>16)&1u); return (u16)(r>>16); }
__device__ inline u16 truncbf(float f){ union{float f; unsigned u;} v; v.f=f; return (u16)(v.u>>16); }
__device__ inline float ld_elem(const void* p, size_t i, int isf32){
  return isf32 ? ((const float*)p)[i] : bf2f(((const u16*)p)[i]);
}
// async global->LDS, 16B per lane; LDS dest must be wave-uniform-base + lane*16
__device__ inline void ld16(const u16* g, u16* l){
  __builtin_amdgcn_global_load_lds((const __attribute__((address_space(1))) void*)g,
                                   (__attribute__((address_space(3))) void*)l, 16, 0, 0);
}

#if __has_builtin(__builtin_amdgcn_exp2f)
#define EXP2(x) __builtin_amdgcn_exp2f(x)
#else
#define EXP2(x) __expf((x)*0.69314718056f)
#endif
// 0.125 (1/sqrt(64)) * log2(e): softmax in exp2 domain, no max subtraction
#define SCALE_LOG2E 0.18033688011112042f

// ---- dtype probe: fp32 buffers read as u16 halves -> huge bf16 exponents
__global__ void detect_dtype(const unsigned* __restrict__ x, int* __restrict__ flag){
  __shared__ int cnt;
  if(threadIdx.x==0) cnt=0;
  __syncthreads();
  int local=0;
  for(int i=threadIdx.x;i<2048;i+=256){
    unsigned w = x[i];
    if(((w>>7)&0xFFu)>=0x90u) local++;
    if(((w>>23)&0xFFu)>=0x90u) local++;
  }
  atomicAdd(&cnt, local);
  __syncthreads();
  if(threadIdx.x==0) *flag = (cnt>64) ? 1 : 0;
}

// ---- x -> canonical bf16
__global__ __launch_bounds__(256) void convert_x(const void* __restrict__ x, u16* __restrict__ xc,
                                                 const int* __restrict__ flag, int n){
  const int f = *flag;
  int i = (blockIdx.x*256 + threadIdx.x)*8;
  if(i>=n) return;
  if(f){
    const float* xf=(const float*)x;
    #pragma unroll
    for(int j=0;j<8;j++) xc[i+j] = f2bf(xf[i+j]);
  } else {
    *(u32x4*)&xc[i] = *(const u32x4*)((const u16*)x + i);
  }
}

// ---- weight transpose+convert: W[k][n] -> WT[n][k] bf16
__global__ __launch_bounds__(256) void transpose_w(
    const void* __restrict__ W0, const void* __restrict__ W1,
    const void* __restrict__ W2, const void* __restrict__ W3,
    u16* __restrict__ T0, u16* __restrict__ T1,
    u16* __restrict__ T2, u16* __restrict__ T3,
    const int* __restrict__ flag){
  __shared__ u16 tile[64][65];
  const int f = *flag;
  const int z = blockIdx.z;
  const void* src = (z==0)?W0:(z==1)?W1:(z==2)?W2:W3;
  u16*       dst = (z==0)?T0:(z==1)?T1:(z==2)?T2:T3;
  const int t = threadIdx.x;
  const int k0 = blockIdx.x*64, n0 = blockIdx.y*64;
  #pragma unroll
  for(int r=0;r<16;r++){
    int row = r*4 + (t>>6), col = t&63;
    tile[row][col] = f2bf(ld_elem(src, (size_t)(k0+row)*Dq + n0 + col, f));
  }
  __syncthreads();
  #pragma unroll
  for(int r=0;r<16;r++){
    int row = r*4 + (t>>6), col = t&63;
    dst[(size_t)(n0+row)*Dq + k0 + col] = tile[col][row];
  }
}

// ---------------- GEMM (m97-style): C = A * Bt^T, global_load_lds staging ----------------
template<int MODE>
__global__ __launch_bounds__(256) void gemm128(
    const u16* __restrict__ A,
    const u16* __restrict__ B0, const u16* __restrict__ B1, const u16* __restrict__ B2,
    u16* __restrict__ O0, u16* __restrict__ O1, u16* __restrict__ O2,
    void* __restrict__ Og, const void* __restrict__ bias, const int* __restrict__ flag){
  __shared__ u16 Al[128*32];   // unpadded: required by global_load_lds lane-contiguity
  __shared__ u16 Bl[128*32];
  const int f = (MODE==1) ? *flag : 0;
  const int t = threadIdx.x;
  const int lane = t & 63, wave = t >> 6;
  const int quad = lane >> 4, l16 = lane & 15;
  const int wr = wave >> 1, wc = wave & 1;
  const int m0 = blockIdx.y*128, n0 = blockIdx.x*128;
  const u16* Bt = B0;
  int z = 0;
  if (MODE==0){ z = blockIdx.z; Bt = (z==0)?B0:((z==1)?B1:B2); }

  f32x4 acc[4][4] = {};

  for(int k0=0;k0<Dq;k0+=32){
    #pragma unroll
    for(int r=0;r<2;r++){
      int idx = t + (r<<8);            // 0..511, lane-consecutive within wave
      int row = idx>>2, kk = (idx&3)<<3;
      ld16(&A [(size_t)(m0+row)*Dq + k0 + kk], Al + idx*8);
      ld16(&Bt[(size_t)(n0+row)*Dq + k0 + kk], Bl + idx*8);
    }
    __syncthreads();
    b16x8 af[4], bfr[4];
    #pragma unroll
    for(int i=0;i<4;i++) af[i]  = *(const b16x8*)&Al[(wr*64 + i*16 + l16)*32 + quad*8];
    #pragma unroll
    for(int j=0;j<4;j++) bfr[j] = *(const b16x8*)&Bl[(wc*64 + j*16 + l16)*32 + quad*8];
    #pragma unroll
    for(int i=0;i<4;i++)
      #pragma unroll
      for(int j=0;j<4;j++)
        acc[i][j] = __builtin_amdgcn_mfma_f32_16x16x32_bf16(af[i], bfr[j], acc[i][j], 0,0,0);
    __syncthreads();
  }

  #pragma unroll
  for(int i=0;i<4;i++){
    #pragma unroll
    for(int j=0;j<4;j++){
      int n = n0 + wc*64 + j*16 + l16;
      #pragma unroll
      for(int r=0;r<4;r++){
        int m = m0 + wr*64 + i*16 + quad*4 + r;   // C/D: row=quad*4+reg, col=l16
        float c = acc[i][j][r];
        if (MODE==1){
          float c2 = c + ld_elem(bias, n, f);
          if (f) ((float*)Og)[(size_t)m*Dq + n] = c2;
          else   ((u16*)Og)[(size_t)m*Dq + n]   = f2bf(c2);
        } else {
          int b = m >> 11, s = m & 2047;
          int h = n >> 6,  hd = n & 63;
          if (z==0)      O0[(((size_t)(b*Hq + h))*Sq + s)*HDq + hd] = f2bf(c);
          else if (z==1) O1[(((size_t)(b*Hq + h))*Sq + s)*HDq + hd] = f2bf(c);
          else           O2[(((size_t)(b*Hq + h))*HDq + hd)*Sq + s] = f2bf(c);
        }
      }
    }
  }
}

// ---------------- flash attention v3: 4 q-tiles per block ----------------
// Tiles {p, 15-p, 16+p, 31-p}: exact cover of 0..31, per-block work ~70 iters (constant).
// K/V staged ONCE per kt for all 4 tiles -> staging iters/bh 408 -> 235.
// No max-subtraction (exp2 domain); l via ones-column MFMA; truncate-pack P.
// K/V: unpadded [64][64] XOR-swizzled (g_phys = g_log ^ (row&7)), global_load_lds staging.
__global__ __launch_bounds__(256,2) void flash_attn(
    const u16* __restrict__ Q, const u16* __restrict__ K,
    const u16* __restrict__ VT, u16* __restrict__ C){
  __shared__ u16 Kt[64*64];     // [key][hd], swizzled groups
  __shared__ u16 Vt[64*64];     // [hd][key], swizzled groups
  __shared__ u16 Pl[4][16][72]; // per-wave P round-trip (C-layout -> A-layout)
  const int t = threadIdx.x;
  const int lane = t&63, wave = t>>6, quad = lane>>4, l16 = lane&15;
  const int p = blockIdx.x, bh = blockIdx.y;
  const int b = bh >> 4, h = bh & 15;
  int qt[4]  = { p, 15-p, 16+p, 31-p };
  int nkt[4];
  #pragma unroll
  for(int tt=0;tt<4;tt++){ int nk = qt[tt]+2; nkt[tt] = (nk<32)?nk:32; }
  const int ktmax = nkt[3];     // 33-p (clamped): largest of the four for p in 0..7
  const u16* Qh = Q  + (size_t)bh*Sq*HDq;
  const u16* Kh = K  + (size_t)bh*Sq*HDq;
  const u16* Vh = VT + (size_t)bh*HDq*Sq;

  b16x8 aq[4][2];
  #pragma unroll
  for(int tt=0;tt<4;tt++){
    const u16* qp = Qh + (size_t)(qt[tt]*64 + wave*16 + l16)*HDq + quad*8;
    aq[tt][0] = *(const b16x8*)qp;
    aq[tt][1] = *(const b16x8*)(qp + 32);
  }
  b16x8 vone;
  #pragma unroll
  for(int i=0;i<8;i++) vone[i] = (__bf16)1.0f;

  const f32x4 fzero = {0.f,0.f,0.f,0.f};
  f32x4 Oa[4][4]; f32x4 lacc[4];
  #pragma unroll
  for(int tt=0;tt<4;tt++){ lacc[tt]=fzero; for(int j=0;j<4;j++) Oa[tt][j]=fzero; }

  for(int kt=0; kt<ktmax; kt++){
    __syncthreads();   // prior iteration's reads of Kt/Vt complete
    #pragma unroll
    for(int r=0;r<2;r++){
      int idx = t + (r<<8);            // slot 0..511 (16B each)
      int row = idx>>3, g = idx&7;
      int c = ((g ^ (row&7)))<<3;      // source column carries the swizzle
      ld16(Kh + (size_t)(kt*64+row)*HDq + c, Kt + idx*8);
      ld16(Vh + (size_t)row*Sq + (size_t)kt*64 + c, Vt + idx*8);
    }
    __syncthreads();   // drain DMA

    #pragma unroll
    for(int tt=0;tt<4;tt++){
      if (kt >= nkt[tt]) continue;            // wave-uniform skip
      const int qq0 = qt[tt]*64;
      // S = Q K^T : B-frag rows = keys, swizzled groups
      f32x4 sc[4];
      #pragma unroll
      for(int jn=0;jn<4;jn++){
        int krow = jn*16 + l16;
        const u16* kp = &Kt[krow*64];
        int ph = quad ^ (krow&7);
        b16x8 bk0 = *(const b16x8*)&kp[ph*8];
        b16x8 bk1 = *(const b16x8*)&kp[(ph^4)*8];
        f32x4 s = fzero;
        s = __builtin_amdgcn_mfma_f32_16x16x32_bf16(aq[tt][0], bk0, s, 0,0,0);
        s = __builtin_amdgcn_mfma_f32_16x16x32_bf16(aq[tt][1], bk1, s, 0,0,0);
        sc[jn] = s;
      }
      // scale to exp2 domain + causal(+1) mask, p = exp2; truncate-pack to LDS
      const int qbase = qq0 + wave*16 + quad*4;
      #pragma unroll
      for(int jn=0;jn<4;jn++){
        int kg = kt*64 + jn*16 + l16;
        #pragma unroll
        for(int r=0;r<4;r++){
          float sv = sc[jn][r]*SCALE_LOG2E;
          if (kg > qbase + r + 1) sv = -__builtin_inff();   // tril(k=1): key <= q+1
          Pl[wave][quad*4+r][jn*16+l16] = truncbf(EXP2(sv));
        }
      }
      // O += P V ; l += P . 1   (no barrier: Pl is wave-private)
      #pragma unroll
      for(int ks=0;ks<2;ks++){
        b16x8 ap = *(const b16x8*)&Pl[wave][l16][ks*32 + quad*8];
        #pragma unroll
        for(int jd=0;jd<4;jd++){
          int hd = jd*16 + l16;
          int ph = (ks*4+quad) ^ (hd&7);
          b16x8 bv = *(const b16x8*)&Vt[hd*64 + ph*8];
          Oa[tt][jd] = __builtin_amdgcn_mfma_f32_16x16x32_bf16(ap, bv, Oa[tt][jd], 0,0,0);
        }
        lacc[tt] = __builtin_amdgcn_mfma_f32_16x16x32_bf16(ap, vone, lacc[tt], 0,0,0);
      }
    }
  }
  // epilogue: ctx[b, s, h*64+hd]
  #pragma unroll
  for(int tt=0;tt<4;tt++){
    const int qq0 = qt[tt]*64;
    #pragma unroll
    for(int r=0;r<4;r++){
      int s = qq0 + wave*16 + quad*4 + r;
      float inv = 1.0f / lacc[tt][r];
      #pragma unroll
      for(int jd=0;jd<4;jd++)
        C[((size_t)(b*Sq + s))*Dq + h*HDq + jd*16 + l16] = f2bf(Oa[tt][jd][r]*inv);
    }
  }
}

// ---------------- launch ----------------
extern "C" void kernel_launch(void* const* d_in, const int* in_sizes, int n_in,
                              void* d_out, int out_size, void* d_ws, size_t ws_size,
                              hipStream_t stream){
  const void* x  = d_in[0];
  const void* Wq = d_in[1];
  const void* Wk = d_in[2];
  const void* Wv = d_in[3];
  const void* Wo = d_in[4];
  const void* bo = d_in[5];

  char* ws = (char*)d_ws;
  size_t off = 0;
  auto wsalloc = [&](size_t bytes)->void*{
    void* p = ws + off; off += (bytes + 255) & ~(size_t)255; return p;
  };
  int* flag = (int*)wsalloc(256);
  u16* WqT = (u16*)wsalloc((size_t)Dq*Dq*2);
  u16* WkT = (u16*)wsalloc((size_t)Dq*Dq*2);
  u16* WvT = (u16*)wsalloc((size_t)Dq*Dq*2);
  u16* WoT = (u16*)wsalloc((size_t)Dq*Dq*2);
  u16* xc  = (u16*)wsalloc((size_t)Mq*Dq*2);
  u16* Qb  = (u16*)wsalloc((size_t)Mq*Dq*2);   // [b,h,s,hd]
  u16* Kb  = (u16*)wsalloc((size_t)Mq*Dq*2);   // [b,h,s,hd]
  u16* VTb = (u16*)wsalloc((size_t)Mq*Dq*2);   // [b,h,hd,s]
  u16* Cb  = (u16*)wsalloc((size_t)Mq*Dq*2);   // [b,s,d]

  detect_dtype<<<1, 256, 0, stream>>>((const unsigned*)x, flag);
  convert_x<<<dim3(Mq*Dq/8/256), 256, 0, stream>>>(x, xc, flag, Mq*Dq);
  transpose_w<<<dim3(16,16,4), 256, 0, stream>>>(Wq,Wk,Wv,Wo, WqT,WkT,WvT,WoT, flag);
  gemm128<0><<<dim3(Dq/128, Mq/128, 3), 256, 0, stream>>>(xc, WqT,WkT,WvT, Qb,Kb,VTb, nullptr, nullptr, flag);
  flash_attn<<<dim3(8, Bq*Hq), 256, 0, stream>>>(Qb, Kb, VTb, Cb);
  gemm128<1><<<dim3(Dq/128, Mq/128, 1), 256, 0, stream>>>(Cb, WoT,WoT,WoT, nullptr,nullptr,nullptr, d_out, bo, flag);
}